// Round 21
// baseline (253.235 us; speedup 1.0000x reference)
//
#include <hip/hip_runtime.h>
#include <stdint.h>
#include <stddef.h>

// ---------- types ----------
typedef __bf16 bf16;
typedef __bf16 bf16x8 __attribute__((ext_vector_type(8)));
typedef __bf16 bf16x4 __attribute__((ext_vector_type(4)));
typedef float  f32x4  __attribute__((ext_vector_type(4)));
typedef float  f32x16 __attribute__((ext_vector_type(16)));
typedef unsigned short ush;
typedef ush ush8 __attribute__((ext_vector_type(8)));
typedef unsigned int uint;

// ---------- problem sizes ----------
#define B_  4
#define S_  2048
#define E_  1024
#define H_  16
#define D_  64
#define M_  (B_*S_)      // 8192 rows
#define K_  E_           // 1024 reduction
// 0.125 (1/sqrt(D)) * log2(e): QKV epilogue folds this into Q -> softmax in exp2 domain
#define QSCALE 0.18033688011112042f
// static softmax shift (exp2 domain); softmax is shift-invariant, range tiny vs f32.
#define SSHIFT 16.0f

// ---------- helpers ----------
__device__ __forceinline__ void gload_lds16(const void* g, void* l) {
  __builtin_amdgcn_global_load_lds((const __attribute__((address_space(1))) void*)g,
                                   (__attribute__((address_space(3))) void*)l, 16, 0, 0);
}
__device__ __forceinline__ f32x4 mfma16(bf16x8 a, bf16x8 b, f32x4 c) {
  return __builtin_amdgcn_mfma_f32_16x16x32_bf16(a, b, c, 0, 0, 0);
}
__device__ __forceinline__ f32x16 mfma32(bf16x8 a, bf16x8 b, f32x16 c) {
  return __builtin_amdgcn_mfma_f32_32x32x16_bf16(a, b, c, 0, 0, 0);
}
__device__ __forceinline__ int swz4(int row, int ch) { return ch ^ ((row >> 1) & 3); }
__device__ __forceinline__ uint cvtpk(float lo, float hi) {
  uint r;
  asm("v_cvt_pk_bf16_f32 %0, %1, %2" : "=v"(r) : "v"(lo), "v"(hi));
  return r;
}

// ---------- prep: ONE dispatch. blocks <2048: grid-stride casts (x->bf16, Wo->bf16);
// blocks >=2048: one LDS-tiled W transpose tile each. ----------
__global__ void prep_kernel(const float* __restrict__ x, bf16* __restrict__ Xbf,
                            const float* __restrict__ Wo, bf16* __restrict__ Wot,
                            const float* __restrict__ Wq, const float* __restrict__ Wk,
                            const float* __restrict__ Wv, bf16* __restrict__ Wp) {
  __shared__ float t[64][65];
  const int tid = threadIdx.x;
  if (blockIdx.x < 2048) {
    const int n4x = (M_ * K_) / 4, n4w = (E_ * E_) / 4;
    int idx = blockIdx.x * 256 + tid;
    const int stride = 2048 * 256;
    for (int i = idx; i < n4x + n4w; i += stride) {
      const float4 v = (i < n4x) ? ((const float4*)x)[i] : ((const float4*)Wo)[i - n4x];
      union { bf16 b[4]; ushort4 u; } cv;
      cv.b[0] = (bf16)v.x; cv.b[1] = (bf16)v.y; cv.b[2] = (bf16)v.z; cv.b[3] = (bf16)v.w;
      if (i < n4x) ((ushort4*)Xbf)[i] = cv.u;
      else         ((ushort4*)Wot)[i - n4x] = cv.u;
    }
  } else {
    const int pb = blockIdx.x - 2048;   // 0..767
    const int wh = pb >> 4;             // 0..47
    const int which = wh >> 4, h = wh & 15;
    const int e0 = (pb & 15) << 6;
    const float* src = (which == 0) ? Wq : (which == 1 ? Wk : Wv);
    src += (size_t)h * (E_ * D_);       // [E][D] for this head
    #pragma unroll
    for (int i = 0; i < 4; ++i) {
      int fi = tid + 256 * i;
      int e = fi >> 4, c = fi & 15;
      float4 v = *(const float4*)(src + (size_t)(e0 + e) * D_ + c * 4);
      t[c * 4 + 0][e] = v.x; t[c * 4 + 1][e] = v.y;
      t[c * 4 + 2][e] = v.z; t[c * 4 + 3][e] = v.w;
    }
    __syncthreads();
    #pragma unroll
    for (int i = 0; i < 2; ++i) {
      int cid = tid + 256 * i;
      int d = cid >> 3, cc = cid & 7;
      ush8 o;
      #pragma unroll
      for (int j = 0; j < 8; ++j) {
        union { bf16 b; ush u; } cv; cv.b = (bf16)t[d][cc * 8 + j]; o[j] = cv.u;
      }
      *(ush8*)(Wp + ((size_t)which * 1024 + h * 64 + d) * K_ + e0 + cc * 8) = o;
    }
  }
}

// ---------- GEMM: C[M][N] = A[M][K] * Bm[N][K]^T (r20 measured-best) ----------
template <int MODE>
__launch_bounds__(256, 3)
__global__ void gemm_kernel(const bf16* __restrict__ A, const bf16* __restrict__ Bm,
                            int Ntot,
                            const float* __restrict__ bias0, const float* __restrict__ bias1,
                            const float* __restrict__ bias2,
                            bf16* __restrict__ Qo, bf16* __restrict__ Ko, bf16* __restrict__ Vto,
                            float* __restrict__ Fo) {
  __shared__ __align__(16) bf16 lds_a[2][128 * 32];
  __shared__ __align__(16) bf16 lds_b[2][128 * 32];
  const int tid = threadIdx.x;
  const int lane = tid & 63;
  const int w = tid >> 6;
  const int wr = w >> 1, wc = w & 1;
  int mt, nt;
  if (MODE == 0) {
    // square XCD chunk: 1536 blocks, xcd covers mt in [(xcd>>1)*16,+16), nt in [(xcd&1)*12,+12)
    const int xcd = blockIdx.x & 7;
    const int idx = blockIdx.x >> 3;            // 0..191
    mt = ((xcd >> 1) << 4) + (idx & 15);        // 0..63
    nt = (xcd & 1) * 12 + (idx >> 4);           // 0..23
  } else {
    const int nblk = Ntot >> 7;
    const int qch = gridDim.x >> 3;
    const int swz = (blockIdx.x & 7) * qch + (blockIdx.x >> 3);
    mt = swz / nblk; nt = swz % nblk;
  }
  const int m0 = mt << 7, n0 = nt << 7;

  f32x4 acc[4][4] = {};

  auto stage = [&](int buf, int kt) {   // 4 gload_lds per lane (2 A + 2 B)
    #pragma unroll
    for (int i = 0; i < 2; ++i) {
      int cb = (w * 2 + i) * 64;
      int cid = cb + lane;
      int row = cid >> 2, cir = cid & 3;
      int lch = swz4(row, cir);
      const bf16* ga = A  + (size_t)(m0 + row) * K_ + kt * 32 + lch * 8;
      const bf16* gb = Bm + (size_t)(n0 + row) * K_ + kt * 32 + lch * 8;
      gload_lds16(ga, &lds_a[buf][cb * 8]);
      gload_lds16(gb, &lds_b[buf][cb * 8]);
    }
  };

  const int NT = K_ / 32;
  stage(0, 0);
  for (int kt = 0; kt < NT; ++kt) {
    if (kt + 1 < NT) {
      stage((kt + 1) & 1, kt + 1);
      asm volatile("s_waitcnt vmcnt(4)" ::: "memory");   // tile kt landed; kt+1 in flight
    } else {
      asm volatile("s_waitcnt vmcnt(0)" ::: "memory");
    }
    __builtin_amdgcn_s_barrier();          // raw: no vmcnt(0) drain
    __builtin_amdgcn_sched_barrier(0);
    const bf16x8* pa = (const bf16x8*)&lds_a[kt & 1][0];
    const bf16x8* pb = (const bf16x8*)&lds_b[kt & 1][0];
    bf16x8 af[4], bfr[4];
    #pragma unroll
    for (int mb = 0; mb < 4; ++mb) {
      int row = wr * 64 + mb * 16 + (lane & 15);
      af[mb] = pa[row * 4 + swz4(row, lane >> 4)];
    }
    #pragma unroll
    for (int nb = 0; nb < 4; ++nb) {
      int row = wc * 64 + nb * 16 + (lane & 15);
      bfr[nb] = pb[row * 4 + swz4(row, lane >> 4)];
    }
    __builtin_amdgcn_s_setprio(1);
    #pragma unroll
    for (int mb = 0; mb < 4; ++mb)
      #pragma unroll
      for (int nb = 0; nb < 4; ++nb)
        acc[mb][nb] = mfma16(af[mb], bfr[nb], acc[mb][nb]);
    __builtin_amdgcn_s_setprio(0);
    asm volatile("s_waitcnt lgkmcnt(0)" ::: "memory");   // reads done (already ~0)
    __builtin_amdgcn_s_barrier();          // buffer safe to overwrite next iter
  }

  #pragma unroll
  for (int mb = 0; mb < 4; ++mb) {
    #pragma unroll
    for (int nb = 0; nb < 4; ++nb) {
      const int ni  = n0 + wc * 64 + nb * 16 + (lane & 15);
      const int mi0 = m0 + wr * 64 + mb * 16 + (lane >> 4) * 4;
      if (MODE == 0) {
        const int which = ni >> 10;          // uniform within the 16-lane group
        const int col = ni & 1023;
        const float* bp = (which == 0) ? bias0 : (which == 1 ? bias1 : bias2);
        const float bv = bp[col];
        const int hh = col >> 6, d = col & 63;
        const int b = mi0 >> 11, s0r = mi0 & 2047;
        if (which == 2) {                    // V: write transposed Vt[B,H,D,S]
          bf16x4 st;
          #pragma unroll
          for (int r = 0; r < 4; ++r) st[r] = (bf16)(acc[mb][nb][r] + bv);
          *(bf16x4*)(Vto + ((size_t)((b * H_ + hh) * D_ + d)) * S_ + s0r) = st;
        } else {
          bf16* dst = (which == 0) ? Qo : Ko;
          const float sc = (which == 0) ? QSCALE : 1.f;
          #pragma unroll
          for (int r = 0; r < 4; ++r)
            dst[(((size_t)(b * H_ + hh)) * S_ + (s0r + r)) * D_ + d] =
                (bf16)((acc[mb][nb][r] + bv) * sc);
        }
      } else {
        #pragma unroll
        for (int r = 0; r < 4; ++r)
          Fo[(size_t)(mi0 + r) * E_ + ni] = acc[mb][nb][r] + bias0[ni];
      }
    }
  }
}

// ---------- flash attention (causal): swapped-QK^T 32x32, STATIC-max softmax ----------
// KVBLK=64, UNPAIRED q-tiles: 1024 blocks (64 bh x 16 j, longest-first) -> 32 KB LDS
// -> 4 blocks/CU = 16 waves/CU (2x TLP vs the paired KVBLK=128 config).
struct QTile {
  bf16x8 qf[4];
  f32x16 oacc[2];
  float l;
};
struct KVF {
  bf16x8 k0[4], k1[4];
  bf16x8 v0[4], v1[4];
};

__device__ __forceinline__ void init_q(QTile& S, const bf16* qrow, int hi) {
  #pragma unroll
  for (int kc = 0; kc < 4; ++kc)
    S.qf[kc] = *(const bf16x8*)(qrow + (2 * kc + hi) * 8);
  #pragma unroll
  for (int r = 0; r < 16; ++r) { S.oacc[0][r] = 0.f; S.oacc[1][r] = 0.f; }
  S.l = 0.f;
}

// klds: [64][64], ch = cir ^ (row&7) ^ ((row>>3)&3). vlds: [64][64], same swizzle
// (identical row-stride-128B/8-chunk geometry that measured 0 bank conflicts).
__device__ __forceinline__ void load_frags(KVF& F, const bf16* klds, const bf16* vlds,
                                           int hi, int ln) {
  const int lxor = (ln & 7) ^ ((ln >> 3) & 3);
  #pragma unroll
  for (int kc = 0; kc < 4; ++kc) {
    int ch = (2 * kc + hi) ^ lxor;
    F.k0[kc] = *(const bf16x8*)&klds[ln * 64 + ch * 8];
    F.k1[kc] = *(const bf16x8*)&klds[(32 + ln) * 64 + ch * 8];
  }
  #pragma unroll
  for (int ks = 0; ks < 4; ++ks) {
    int ch = (2 * ks + hi) ^ lxor;
    F.v0[ks] = *(const bf16x8*)&vlds[ln * 64 + ch * 8];
    F.v1[ks] = *(const bf16x8*)&vlds[(32 + ln) * 64 + ch * 8];
  }
}

__device__ __forceinline__ void step_one(QTile& S, const KVF& F,
                                         int kv0, int qb_, int qg_, int hi) {
  if (kv0 > qb_ + 31) return;
  f32x16 s0 = {}, s1 = {};
  __builtin_amdgcn_s_setprio(1);
  #pragma unroll
  for (int kc = 0; kc < 4; ++kc) {
    s0 = mfma32(F.k0[kc], S.qf[kc], s0);
    s1 = mfma32(F.k1[kc], S.qf[kc], s1);
  }
  __builtin_amdgcn_s_setprio(0);
  if (kv0 + 63 > qb_) {
    #pragma unroll
    for (int r = 0; r < 16; ++r) {
      int crow = (r & 3) + 8 * (r >> 2) + 4 * hi;
      if (kv0 + crow > qg_)      s0[r] = -1e30f;
      if (kv0 + 32 + crow > qg_) s1[r] = -1e30f;
    }
  }
  #pragma unroll
  for (int r = 0; r < 16; ++r) {
    s0[r] = exp2f(s0[r] - SSHIFT);
    s1[r] = exp2f(s1[r] - SSHIFT);
  }
  bf16x8 pf[4];
  #pragma unroll
  for (int mtl = 0; mtl < 2; ++mtl) {
    #pragma unroll
    for (int c = 0; c < 2; ++c) {
      const f32x16& p = mtl ? s1 : s0;
      uint wa = cvtpk(p[8 * c + 0], p[8 * c + 1]);
      uint wb = cvtpk(p[8 * c + 2], p[8 * c + 3]);
      uint wcx = cvtpk(p[8 * c + 4], p[8 * c + 5]);
      uint wd = cvtpk(p[8 * c + 6], p[8 * c + 7]);
      asm("v_permlane32_swap_b32 %0, %1" : "+v"(wa), "+v"(wcx));
      asm("v_permlane32_swap_b32 %0, %1" : "+v"(wb), "+v"(wd));
      union { uint u[4]; bf16x8 v; } cvt;
      cvt.u[0] = wa; cvt.u[1] = wb; cvt.u[2] = wcx; cvt.u[3] = wd;
      pf[mtl * 2 + c] = cvt.v;
    }
  }
  const bf16 one_ = (bf16)1.f;
  const bf16x8 vones = {one_, one_, one_, one_, one_, one_, one_, one_};
  f32x16 lt = {};
  __builtin_amdgcn_s_setprio(1);
  #pragma unroll
  for (int ks = 0; ks < 4; ++ks) lt = mfma32(vones, pf[ks], lt);
  #pragma unroll
  for (int ks = 0; ks < 4; ++ks) {
    S.oacc[0] = mfma32(F.v0[ks], pf[ks], S.oacc[0]);
    S.oacc[1] = mfma32(F.v1[ks], pf[ks], S.oacc[1]);
  }
  __builtin_amdgcn_s_setprio(0);
  S.l += lt[0];
}

__device__ __forceinline__ void store_o(const QTile& S, bf16* orow, int hi) {
  float rinv = 1.f / S.l;
  #pragma unroll
  for (int dm = 0; dm < 2; ++dm) {
    #pragma unroll
    for (int g = 0; g < 4; ++g) {
      bf16x4 st;
      #pragma unroll
      for (int i = 0; i < 4; ++i) st[i] = (bf16)(S.oacc[dm][4 * g + i] * rinv);
      *(bf16x4*)(orow + dm * 32 + g * 8 + hi * 4) = st;
    }
  }
}

// grid: 1024 x 256 threads. bh = bid&63 (bid&7 pins bh's blocks to one XCD);
// j = 15-(bid>>6) -> longest q-tiles dispatch first (backfill balance).
__launch_bounds__(256, 4)
__global__ void attn_kernel(const bf16* __restrict__ Q, const bf16* __restrict__ K,
                            const bf16* __restrict__ Vt, bf16* __restrict__ Cc) {
  __shared__ __align__(16) bf16 k_lds[2][64 * 64];   // 2 x 8 KB
  __shared__ __align__(16) bf16 v_lds[2][64 * 64];   // 2 x 8 KB (32 KB total)
  const int tid = threadIdx.x, lane = tid & 63, w = tid >> 6;
  const int hi = lane >> 5, ln = lane & 31;
  const int bid = blockIdx.x;
  const int bh = bid & 63;
  const int j = 15 - (bid >> 6);
  const bf16* Kb = K  + (size_t)bh * (S_ * D_);
  const bf16* Vb = Vt + (size_t)bh * (D_ * S_);
  const int b = bh >> 4, hh = bh & 15;

  const int qb = j * 128 + w * 32, qg = qb + ln;
  const int nt = 2 * j + 2;   // KVBLK=64 tiles

  QTile S;
  init_q(S, Q + ((size_t)bh * S_ + qg) * D_, hi);

  auto stage64 = [&](int buf, int t) {   // 4 gload_lds per lane (2 K + 2 V)
    const int kv0 = t << 6;
    #pragma unroll
    for (int i = 0; i < 2; ++i) {
      int cb = (w * 2 + i) * 64;
      int cid = cb + lane;
      int row = cid >> 3, cir = cid & 7;     // 64 rows x 8 chunks
      int lch = cir ^ (row & 7) ^ ((row >> 3) & 3);
      gload_lds16(Kb + (size_t)(kv0 + row) * D_ + lch * 8, &k_lds[buf][cb * 8]);
      gload_lds16(Vb + (size_t)row * S_ + kv0 + lch * 8, &v_lds[buf][cb * 8]);
    }
  };

  stage64(0, 0);
  __syncthreads();
  for (int t = 0; t < nt; ++t) {
    const int cur = t & 1;
    if (t + 1 < nt) stage64(cur ^ 1, t + 1);
    KVF F;
    load_frags(F, k_lds[cur], v_lds[cur], hi, ln);
    step_one(S, F, t * 64, qb, qg, hi);
    __syncthreads();
  }

  store_o(S, Cc + ((size_t)(b * S_ + qg)) * E_ + hh * D_, hi);
}

// ---------- launcher ----------
extern "C" void kernel_launch(void* const* d_in, const int* in_sizes, int n_in,
                              void* d_out, int out_size, void* d_ws, size_t ws_size,
                              hipStream_t stream) {
  const float* x  = (const float*)d_in[0];
  const float* Wq = (const float*)d_in[1];
  const float* bq = (const float*)d_in[2];
  const float* Wk = (const float*)d_in[3];
  const float* bk = (const float*)d_in[4];
  const float* Wv = (const float*)d_in[5];
  const float* bv = (const float*)d_in[6];
  const float* Wo = (const float*)d_in[7];
  const float* bo = (const float*)d_in[8];
  float* out = (float*)d_out;

  uint8_t* ws = (uint8_t*)d_ws;
  bf16* Xbf   = (bf16*)(ws + 0);           // [M][K]; later reused as concat
  bf16* Wpack = (bf16*)(ws + 16777216);    // [3072][1024]
  bf16* Wot   = (bf16*)(ws + 23068672);    // [1024][1024]
  bf16* Qb    = (bf16*)(ws + 25165824);    // [B,H,S,D] (pre-scaled)
  bf16* Kb    = (bf16*)(ws + 41943040);    // [B,H,S,D]
  bf16* Vtb   = (bf16*)(ws + 75497472);    // [B,H,D,S] (written by GEMM epilogue)
  bf16* Cc    = Xbf;

  // single prep dispatch: casts (blocks 0..2047) + W transpose tiles (2048..2815)
  prep_kernel<<<dim3(2816), 256, 0, stream>>>(x, Xbf, Wo, Wot, Wq, Wk, Wv, Wpack);

  gemm_kernel<0><<<dim3(64 * 24), 256, 0, stream>>>(Xbf, Wpack, 3072, bq, bk, bv,
                                                    Qb, Kb, Vtb, nullptr);

  attn_kernel<<<dim3(1024), 256, 0, stream>>>(Qb, Kb, Vtb, Cc);

  gemm_kernel<1><<<dim3(64 * 8), 256, 0, stream>>>(Cc, Wot, 1024, bo, nullptr, nullptr,
                                                   nullptr, nullptr, nullptr, out);
}

// Round 22
// 176.042 us; speedup vs baseline: 1.4385x; 1.4385x over previous
//
#include <hip/hip_runtime.h>
#include <stdint.h>
#include <stddef.h>

// ---------- types ----------
typedef __bf16 bf16;
typedef __bf16 bf16x8 __attribute__((ext_vector_type(8)));
typedef __bf16 bf16x4 __attribute__((ext_vector_type(4)));
typedef float  f32x4  __attribute__((ext_vector_type(4)));
typedef float  f32x16 __attribute__((ext_vector_type(16)));
typedef unsigned short ush;
typedef ush ush8 __attribute__((ext_vector_type(8)));
typedef unsigned int uint;

// ---------- problem sizes ----------
#define B_  4
#define S_  2048
#define E_  1024
#define H_  16
#define D_  64
#define M_  (B_*S_)      // 8192 rows
#define K_  E_           // 1024 reduction
// 0.125 (1/sqrt(D)) * log2(e): QKV epilogue folds this into Q -> softmax in exp2 domain
#define QSCALE 0.18033688011112042f
// static softmax shift (exp2 domain); softmax is shift-invariant, range tiny vs f32.
#define SSHIFT 16.0f

// ---------- helpers ----------
__device__ __forceinline__ void gload_lds16(const void* g, void* l) {
  __builtin_amdgcn_global_load_lds((const __attribute__((address_space(1))) void*)g,
                                   (__attribute__((address_space(3))) void*)l, 16, 0, 0);
}
__device__ __forceinline__ f32x4 mfma16(bf16x8 a, bf16x8 b, f32x4 c) {
  return __builtin_amdgcn_mfma_f32_16x16x32_bf16(a, b, c, 0, 0, 0);
}
__device__ __forceinline__ f32x16 mfma32(bf16x8 a, bf16x8 b, f32x16 c) {
  return __builtin_amdgcn_mfma_f32_32x32x16_bf16(a, b, c, 0, 0, 0);
}
__device__ __forceinline__ int swz4(int row, int ch) { return ch ^ ((row >> 1) & 3); }
__device__ __forceinline__ uint cvtpk(float lo, float hi) {
  uint r;
  asm("v_cvt_pk_bf16_f32 %0, %1, %2" : "=v"(r) : "v"(lo), "v"(hi));
  return r;
}

// ---------- prep: ONE dispatch. blocks <2048: grid-stride casts (x->bf16, Wo->bf16);
// blocks >=2048: one LDS-tiled W transpose tile each. ----------
__global__ void prep_kernel(const float* __restrict__ x, bf16* __restrict__ Xbf,
                            const float* __restrict__ Wo, bf16* __restrict__ Wot,
                            const float* __restrict__ Wq, const float* __restrict__ Wk,
                            const float* __restrict__ Wv, bf16* __restrict__ Wp) {
  __shared__ float t[64][65];
  const int tid = threadIdx.x;
  if (blockIdx.x < 2048) {
    const int n4x = (M_ * K_) / 4, n4w = (E_ * E_) / 4;
    int idx = blockIdx.x * 256 + tid;
    const int stride = 2048 * 256;
    for (int i = idx; i < n4x + n4w; i += stride) {
      const float4 v = (i < n4x) ? ((const float4*)x)[i] : ((const float4*)Wo)[i - n4x];
      union { bf16 b[4]; ushort4 u; } cv;
      cv.b[0] = (bf16)v.x; cv.b[1] = (bf16)v.y; cv.b[2] = (bf16)v.z; cv.b[3] = (bf16)v.w;
      if (i < n4x) ((ushort4*)Xbf)[i] = cv.u;
      else         ((ushort4*)Wot)[i - n4x] = cv.u;
    }
  } else {
    const int pb = blockIdx.x - 2048;   // 0..767
    const int wh = pb >> 4;             // 0..47
    const int which = wh >> 4, h = wh & 15;
    const int e0 = (pb & 15) << 6;
    const float* src = (which == 0) ? Wq : (which == 1 ? Wk : Wv);
    src += (size_t)h * (E_ * D_);       // [E][D] for this head
    #pragma unroll
    for (int i = 0; i < 4; ++i) {
      int fi = tid + 256 * i;
      int e = fi >> 4, c = fi & 15;
      float4 v = *(const float4*)(src + (size_t)(e0 + e) * D_ + c * 4);
      t[c * 4 + 0][e] = v.x; t[c * 4 + 1][e] = v.y;
      t[c * 4 + 2][e] = v.z; t[c * 4 + 3][e] = v.w;
    }
    __syncthreads();
    #pragma unroll
    for (int i = 0; i < 2; ++i) {
      int cid = tid + 256 * i;
      int d = cid >> 3, cc = cid & 7;
      ush8 o;
      #pragma unroll
      for (int j = 0; j < 8; ++j) {
        union { bf16 b; ush u; } cv; cv.b = (bf16)t[d][cc * 8 + j]; o[j] = cv.u;
      }
      *(ush8*)(Wp + ((size_t)which * 1024 + h * 64 + d) * K_ + e0 + cc * 8) = o;
    }
  }
}

// ---------- GEMM: C[M][N] = A[M][K] * Bm[N][K]^T (r20 measured-best) ----------
// Counted vmcnt + raw barriers. MODE 0 uses a SQUARE 16mt x 12nt XCD chunking so each
// XCD's working set (A 4MB + B 3MB, K-sliced) streams through its private L2.
// MODE 0: scatter bf16 Q (pre-scaled) / K [B,H,S,D], V -> Vt [B,H,D,S]. MODE 1: fp32 out.
template <int MODE>
__launch_bounds__(256, 3)
__global__ void gemm_kernel(const bf16* __restrict__ A, const bf16* __restrict__ Bm,
                            int Ntot,
                            const float* __restrict__ bias0, const float* __restrict__ bias1,
                            const float* __restrict__ bias2,
                            bf16* __restrict__ Qo, bf16* __restrict__ Ko, bf16* __restrict__ Vto,
                            float* __restrict__ Fo) {
  __shared__ __align__(16) bf16 lds_a[2][128 * 32];
  __shared__ __align__(16) bf16 lds_b[2][128 * 32];
  const int tid = threadIdx.x;
  const int lane = tid & 63;
  const int w = tid >> 6;
  const int wr = w >> 1, wc = w & 1;
  int mt, nt;
  if (MODE == 0) {
    // square XCD chunk: 1536 blocks, xcd covers mt in [(xcd>>1)*16,+16), nt in [(xcd&1)*12,+12)
    const int xcd = blockIdx.x & 7;
    const int idx = blockIdx.x >> 3;            // 0..191
    mt = ((xcd >> 1) << 4) + (idx & 15);        // 0..63
    nt = (xcd & 1) * 12 + (idx >> 4);           // 0..23
  } else {
    const int nblk = Ntot >> 7;
    const int qch = gridDim.x >> 3;
    const int swz = (blockIdx.x & 7) * qch + (blockIdx.x >> 3);
    mt = swz / nblk; nt = swz % nblk;
  }
  const int m0 = mt << 7, n0 = nt << 7;

  f32x4 acc[4][4] = {};

  auto stage = [&](int buf, int kt) {   // 4 gload_lds per lane (2 A + 2 B)
    #pragma unroll
    for (int i = 0; i < 2; ++i) {
      int cb = (w * 2 + i) * 64;
      int cid = cb + lane;
      int row = cid >> 2, cir = cid & 3;
      int lch = swz4(row, cir);
      const bf16* ga = A  + (size_t)(m0 + row) * K_ + kt * 32 + lch * 8;
      const bf16* gb = Bm + (size_t)(n0 + row) * K_ + kt * 32 + lch * 8;
      gload_lds16(ga, &lds_a[buf][cb * 8]);
      gload_lds16(gb, &lds_b[buf][cb * 8]);
    }
  };

  const int NT = K_ / 32;
  stage(0, 0);
  for (int kt = 0; kt < NT; ++kt) {
    if (kt + 1 < NT) {
      stage((kt + 1) & 1, kt + 1);
      asm volatile("s_waitcnt vmcnt(4)" ::: "memory");   // tile kt landed; kt+1 in flight
    } else {
      asm volatile("s_waitcnt vmcnt(0)" ::: "memory");
    }
    __builtin_amdgcn_s_barrier();          // raw: no vmcnt(0) drain
    __builtin_amdgcn_sched_barrier(0);
    const bf16x8* pa = (const bf16x8*)&lds_a[kt & 1][0];
    const bf16x8* pb = (const bf16x8*)&lds_b[kt & 1][0];
    bf16x8 af[4], bfr[4];
    #pragma unroll
    for (int mb = 0; mb < 4; ++mb) {
      int row = wr * 64 + mb * 16 + (lane & 15);
      af[mb] = pa[row * 4 + swz4(row, lane >> 4)];
    }
    #pragma unroll
    for (int nb = 0; nb < 4; ++nb) {
      int row = wc * 64 + nb * 16 + (lane & 15);
      bfr[nb] = pb[row * 4 + swz4(row, lane >> 4)];
    }
    __builtin_amdgcn_s_setprio(1);
    #pragma unroll
    for (int mb = 0; mb < 4; ++mb)
      #pragma unroll
      for (int nb = 0; nb < 4; ++nb)
        acc[mb][nb] = mfma16(af[mb], bfr[nb], acc[mb][nb]);
    __builtin_amdgcn_s_setprio(0);
    asm volatile("s_waitcnt lgkmcnt(0)" ::: "memory");   // reads done (already ~0)
    __builtin_amdgcn_s_barrier();          // buffer safe to overwrite next iter
  }

  #pragma unroll
  for (int mb = 0; mb < 4; ++mb) {
    #pragma unroll
    for (int nb = 0; nb < 4; ++nb) {
      const int ni  = n0 + wc * 64 + nb * 16 + (lane & 15);
      const int mi0 = m0 + wr * 64 + mb * 16 + (lane >> 4) * 4;
      if (MODE == 0) {
        const int which = ni >> 10;          // uniform within the 16-lane group
        const int col = ni & 1023;
        const float* bp = (which == 0) ? bias0 : (which == 1 ? bias1 : bias2);
        const float bv = bp[col];
        const int hh = col >> 6, d = col & 63;
        const int b = mi0 >> 11, s0r = mi0 & 2047;
        if (which == 2) {                    // V: write transposed Vt[B,H,D,S]
          bf16x4 st;
          #pragma unroll
          for (int r = 0; r < 4; ++r) st[r] = (bf16)(acc[mb][nb][r] + bv);
          *(bf16x4*)(Vto + ((size_t)((b * H_ + hh) * D_ + d)) * S_ + s0r) = st;
        } else {
          bf16* dst = (which == 0) ? Qo : Ko;
          const float sc = (which == 0) ? QSCALE : 1.f;
          #pragma unroll
          for (int r = 0; r < 4; ++r)
            dst[(((size_t)(b * H_ + hh)) * S_ + (s0r + r)) * D_ + d] =
                (bf16)((acc[mb][nb][r] + bv) * sc);
        }
      } else {
        #pragma unroll
        for (int r = 0; r < 4; ++r)
          Fo[(size_t)(mi0 + r) * E_ + ni] = acc[mb][nb][r] + bias0[ni];
      }
    }
  }
}

// ---------- flash attention (causal): swapped-QK^T 32x32, STATIC-max softmax ----------
struct QTile {
  bf16x8 qf[4];
  f32x16 oacc[2];
  float l;
};
struct KVF {
  bf16x8 k0[4], k1[4];
  bf16x8 v0[4], v1[4];
};

__device__ __forceinline__ void init_q(QTile& S, const bf16* qrow, int hi) {
  #pragma unroll
  for (int kc = 0; kc < 4; ++kc)
    S.qf[kc] = *(const bf16x8*)(qrow + (2 * kc + hi) * 8);
  #pragma unroll
  for (int r = 0; r < 16; ++r) { S.oacc[0][r] = 0.f; S.oacc[1][r] = 0.f; }
  S.l = 0.f;
}

__device__ __forceinline__ void load_frags(KVF& F, const bf16* klds, const bf16* vlds,
                                           int sub, int hi, int ln) {
  const bf16* kbase = klds + sub * (64 * 64);
  const int lxor = (ln & 7) ^ ((ln >> 3) & 3);
  #pragma unroll
  for (int kc = 0; kc < 4; ++kc) {
    int ch = (2 * kc + hi) ^ lxor;
    F.k0[kc] = *(const bf16x8*)&kbase[ln * 64 + ch * 8];
    F.k1[kc] = *(const bf16x8*)&kbase[(32 + ln) * 64 + ch * 8];
  }
  #pragma unroll
  for (int ks = 0; ks < 4; ++ks) {
    int cf = sub * 8 + 2 * ks + hi;
    int ch = cf ^ (ln & 15);
    F.v0[ks] = *(const bf16x8*)&vlds[ln * 128 + ch * 8];
    F.v1[ks] = *(const bf16x8*)&vlds[(32 + ln) * 128 + ch * 8];
  }
}

__device__ __forceinline__ void step_one(QTile& S, const KVF& F,
                                         int kv0, int qb_, int qg_, int hi) {
  if (kv0 > qb_ + 31) return;
  f32x16 s0 = {}, s1 = {};
  __builtin_amdgcn_s_setprio(1);
  #pragma unroll
  for (int kc = 0; kc < 4; ++kc) {
    s0 = mfma32(F.k0[kc], S.qf[kc], s0);
    s1 = mfma32(F.k1[kc], S.qf[kc], s1);
  }
  __builtin_amdgcn_s_setprio(0);
  if (kv0 + 63 > qb_) {
    #pragma unroll
    for (int r = 0; r < 16; ++r) {
      int crow = (r & 3) + 8 * (r >> 2) + 4 * hi;
      if (kv0 + crow > qg_)      s0[r] = -1e30f;
      if (kv0 + 32 + crow > qg_) s1[r] = -1e30f;
    }
  }
  #pragma unroll
  for (int r = 0; r < 16; ++r) {
    s0[r] = exp2f(s0[r] - SSHIFT);
    s1[r] = exp2f(s1[r] - SSHIFT);
  }
  bf16x8 pf[4];
  #pragma unroll
  for (int mtl = 0; mtl < 2; ++mtl) {
    #pragma unroll
    for (int c = 0; c < 2; ++c) {
      const f32x16& p = mtl ? s1 : s0;
      uint wa = cvtpk(p[8 * c + 0], p[8 * c + 1]);
      uint wb = cvtpk(p[8 * c + 2], p[8 * c + 3]);
      uint wcx = cvtpk(p[8 * c + 4], p[8 * c + 5]);
      uint wd = cvtpk(p[8 * c + 6], p[8 * c + 7]);
      asm("v_permlane32_swap_b32 %0, %1" : "+v"(wa), "+v"(wcx));
      asm("v_permlane32_swap_b32 %0, %1" : "+v"(wb), "+v"(wd));
      union { uint u[4]; bf16x8 v; } cvt;
      cvt.u[0] = wa; cvt.u[1] = wb; cvt.u[2] = wcx; cvt.u[3] = wd;
      pf[mtl * 2 + c] = cvt.v;
    }
  }
  const bf16 one_ = (bf16)1.f;
  const bf16x8 vones = {one_, one_, one_, one_, one_, one_, one_, one_};
  f32x16 lt = {};
  __builtin_amdgcn_s_setprio(1);
  #pragma unroll
  for (int ks = 0; ks < 4; ++ks) lt = mfma32(vones, pf[ks], lt);
  #pragma unroll
  for (int ks = 0; ks < 4; ++ks) {
    S.oacc[0] = mfma32(F.v0[ks], pf[ks], S.oacc[0]);
    S.oacc[1] = mfma32(F.v1[ks], pf[ks], S.oacc[1]);
  }
  __builtin_amdgcn_s_setprio(0);
  S.l += lt[0];
}

__device__ __forceinline__ void store_o(const QTile& S, bf16* orow, int hi) {
  float rinv = 1.f / S.l;
  #pragma unroll
  for (int dm = 0; dm < 2; ++dm) {
    #pragma unroll
    for (int g = 0; g < 4; ++g) {
      bf16x4 st;
      #pragma unroll
      for (int i = 0; i < 4; ++i) st[i] = (bf16)(S.oacc[dm][4 * g + i] * rinv);
      *(bf16x4*)(orow + dm * 32 + g * 8 + hi * 4) = st;
    }
  }
}

__launch_bounds__(256, 2)
__global__ void attn_kernel(const bf16* __restrict__ Q, const bf16* __restrict__ K,
                            const bf16* __restrict__ Vt, bf16* __restrict__ Cc) {
  __shared__ __align__(16) bf16 k_lds[2][128 * 64];
  __shared__ __align__(16) bf16 v_lds[2][64 * 128];
  const int tid = threadIdx.x, lane = tid & 63, w = tid >> 6;
  const int hi = lane >> 5, ln = lane & 31;
  const int bid = blockIdx.x;
  const int bh = bid & 63;
  const int x = bid >> 6;
  const bf16* Kb = K  + (size_t)bh * (S_ * D_);
  const bf16* Vb = Vt + (size_t)bh * (D_ * S_);
  const int b = bh >> 4, hh = bh & 15;

  const int qbA = x * 128 + w * 32,        qgA = qbA + ln;
  const int qbB = (15 - x) * 128 + w * 32, qgB = qbB + ln;
  const int nphA = x + 1, nphB = 16 - x;

  QTile SA, SB;
  init_q(SA, Q + ((size_t)bh * S_ + qgA) * D_, hi);
  init_q(SB, Q + ((size_t)bh * S_ + qgB) * D_, hi);

  auto stage2 = [&](int buf, int ph) {
    const int kv0 = ph << 7;
    #pragma unroll
    for (int i = 0; i < 4; ++i) {
      int cb = (w * 4 + i) * 64;
      int cid = cb + lane;
      int row = cid >> 3, cir = cid & 7;
      int lch = cir ^ (row & 7) ^ ((row >> 3) & 3);
      gload_lds16(Kb + (size_t)(kv0 + row) * D_ + lch * 8, &k_lds[buf][cb * 8]);
      int rowv = cid >> 4, cirv = cid & 15;
      int lchv = cirv ^ (rowv & 15);
      gload_lds16(Vb + (size_t)rowv * S_ + kv0 + lchv * 8, &v_lds[buf][cb * 8]);
    }
  };

  stage2(0, 0);
  __syncthreads();
  for (int ph = 0; ph < nphB; ++ph) {
    const int cur = ph & 1;
    if (ph + 1 < nphB) stage2(cur ^ 1, ph + 1);
    const int kv0 = ph << 7;
    {
      KVF F0;
      load_frags(F0, k_lds[cur], v_lds[cur], 0, hi, ln);
      if (ph < nphA) step_one(SA, F0, kv0, qbA, qgA, hi);
      step_one(SB, F0, kv0, qbB, qgB, hi);
    }
    {
      KVF F1;
      load_frags(F1, k_lds[cur], v_lds[cur], 1, hi, ln);
      if (ph < nphA) step_one(SA, F1, kv0 + 64, qbA, qgA, hi);
      step_one(SB, F1, kv0 + 64, qbB, qgB, hi);
    }
    __syncthreads();
  }

  store_o(SA, Cc + ((size_t)(b * S_ + qgA)) * E_ + hh * D_, hi);
  store_o(SB, Cc + ((size_t)(b * S_ + qgB)) * E_ + hh * D_, hi);
}

// ---------- launcher ----------
extern "C" void kernel_launch(void* const* d_in, const int* in_sizes, int n_in,
                              void* d_out, int out_size, void* d_ws, size_t ws_size,
                              hipStream_t stream) {
  const float* x  = (const float*)d_in[0];
  const float* Wq = (const float*)d_in[1];
  const float* bq = (const float*)d_in[2];
  const float* Wk = (const float*)d_in[3];
  const float* bk = (const float*)d_in[4];
  const float* Wv = (const float*)d_in[5];
  const float* bv = (const float*)d_in[6];
  const float* Wo = (const float*)d_in[7];
  const float* bo = (const float*)d_in[8];
  float* out = (float*)d_out;

  uint8_t* ws = (uint8_t*)d_ws;
  bf16* Xbf   = (bf16*)(ws + 0);           // [M][K]; later reused as concat
  bf16* Wpack = (bf16*)(ws + 16777216);    // [3072][1024]
  bf16* Wot   = (bf16*)(ws + 23068672);    // [1024][1024]
  bf16* Qb    = (bf16*)(ws + 25165824);    // [B,H,S,D] (pre-scaled)
  bf16* Kb    = (bf16*)(ws + 41943040);    // [B,H,S,D]
  bf16* Vtb   = (bf16*)(ws + 75497472);    // [B,H,D,S] (written by GEMM epilogue)
  bf16* Cc    = Xbf;

  // single prep dispatch: casts (blocks 0..2047) + W transpose tiles (2048..2815)
  prep_kernel<<<dim3(2816), 256, 0, stream>>>(x, Xbf, Wo, Wot, Wq, Wk, Wv, Wpack);

  gemm_kernel<0><<<dim3(64 * 24), 256, 0, stream>>>(Xbf, Wpack, 3072, bq, bk, bv,
                                                    Qb, Kb, Vtb, nullptr);

  attn_kernel<<<dim3(512), 256, 0, stream>>>(Qb, Kb, Vtb, Cc);

  gemm_kernel<1><<<dim3(64 * 8), 256, 0, stream>>>(Cc, Wot, 1024, bo, nullptr, nullptr,
                                                   nullptr, nullptr, nullptr, out);
}